// Round 1
// baseline (236.615 us; speedup 1.0000x reference)
//
#include <hip/hip_runtime.h>
#include <hip/hip_bf16.h>

typedef __bf16 bf16x8 __attribute__((ext_vector_type(8)));
typedef float  f32x16 __attribute__((ext_vector_type(16)));

#define ALPHA_W 0.4f
#define NTOT 65536.0f

// output layout (float elements): [out 4*256*128*128][cov 8*32*32][eigen 32*32*32]
#define OUT_MAIN 16777216
#define OUT_COV  (OUT_MAIN)
#define OUT_EIG  (OUT_MAIN + 8192)

// ws float offsets
#define WS_PSXY  0        // 512*1024 gram partials
#define WS_PSX   524288   // 512*32 channel-sum partials
#define WS_SMU   559104   // 4*256
#define WS_CT    560128   // 32*1024 s_CT

struct WP {
    const float* cw0; const float* cb0;
    const float* cw1; const float* cb1;
    const float* cw2; const float* cb2;
    const float* cw3; const float* cb3;
    const float* cw4; const float* cb4;
    const float* mw0; const float* mb0;
    const float* mw1; const float* mb1;
    const float* mw2; const float* mb2;
};

__device__ __forceinline__ float lrelu(float x) { return x >= 0.f ? x : 0.01f * x; }

// fully-unrolled 256-dot, w from global, x from LDS (uniform address -> broadcast)
__device__ __forceinline__ float dotg256(const float* __restrict__ w, const float* __restrict__ x) {
    float a0 = 0.f, a1 = 0.f, a2 = 0.f, a3 = 0.f;
    #pragma unroll
    for (int i = 0; i < 256; i += 16) {
        float4 w0 = *(const float4*)(w + i);
        float4 w1 = *(const float4*)(w + i + 4);
        float4 w2 = *(const float4*)(w + i + 8);
        float4 w3 = *(const float4*)(w + i + 12);
        float4 x0 = *(const float4*)(x + i);
        float4 x1 = *(const float4*)(x + i + 4);
        float4 x2 = *(const float4*)(x + i + 8);
        float4 x3 = *(const float4*)(x + i + 12);
        a0 = fmaf(w0.x, x0.x, a0); a0 = fmaf(w0.y, x0.y, a0);
        a0 = fmaf(w0.z, x0.z, a0); a0 = fmaf(w0.w, x0.w, a0);
        a1 = fmaf(w1.x, x1.x, a1); a1 = fmaf(w1.y, x1.y, a1);
        a1 = fmaf(w1.z, x1.z, a1); a1 = fmaf(w1.w, x1.w, a1);
        a2 = fmaf(w2.x, x2.x, a2); a2 = fmaf(w2.y, x2.y, a2);
        a2 = fmaf(w2.z, x2.z, a2); a2 = fmaf(w2.w, x2.w, a2);
        a3 = fmaf(w3.x, x3.x, a3); a3 = fmaf(w3.y, x3.y, a3);
        a3 = fmaf(w3.z, x3.z, a3); a3 = fmaf(w3.w, x3.w, a3);
    }
    return (a0 + a1) + (a2 + a3);
}

// ---------- K1: blocks 0..31 ct-MLP row chains, 32..35 mu-MLP row chains, 36..547 gram ----------
__global__ __launch_bounds__(256, 2) void fused_front(const float* __restrict__ cA,
                                                      const float* __restrict__ sB,
                                                      WP wp,
                                                      float* __restrict__ pSXY,
                                                      float* __restrict__ pSX,
                                                      float* __restrict__ CT,
                                                      float* __restrict__ SMU) {
    int bid = blockIdx.x;
    int tid = threadIdx.x;
    if (bid < 36) {
        // -------- fused MLP chains: one block per independent row --------
        __shared__ float xb_[256], hb_[256];
        int t = tid;
        if (bid < 32) {
            int r = bid;                         // r = b*8+g
            if (t < 32) xb_[t] = sB[r * 32 + t];
            __syncthreads();
            // L0: 256 x 32
            {
                const float* wr = wp.cw0 + t * 32;
                float a0 = 0.f, a1 = 0.f;
                #pragma unroll
                for (int i = 0; i < 32; i += 8) {
                    float4 u0 = *(const float4*)(wr + i);
                    float4 u1 = *(const float4*)(wr + i + 4);
                    float4 x0 = *(const float4*)(xb_ + i);
                    float4 x1 = *(const float4*)(xb_ + i + 4);
                    a0 = fmaf(u0.x, x0.x, a0); a0 = fmaf(u0.y, x0.y, a0);
                    a0 = fmaf(u0.z, x0.z, a0); a0 = fmaf(u0.w, x0.w, a0);
                    a1 = fmaf(u1.x, x1.x, a1); a1 = fmaf(u1.y, x1.y, a1);
                    a1 = fmaf(u1.z, x1.z, a1); a1 = fmaf(u1.w, x1.w, a1);
                }
                hb_[t] = lrelu(a0 + a1 + wp.cb0[t]);
            }
            __syncthreads();
            xb_[t] = lrelu(dotg256(wp.cw1 + (size_t)t * 256, hb_) + wp.cb1[t]);
            __syncthreads();
            hb_[t] = lrelu(dotg256(wp.cw2 + (size_t)t * 256, xb_) + wp.cb2[t]);
            __syncthreads();
            xb_[t] = lrelu(dotg256(wp.cw3 + (size_t)t * 256, hb_) + wp.cb3[t]);
            __syncthreads();
            // L4: 1024 x 256, no act
            #pragma unroll
            for (int c = 0; c < 4; c++) {
                int o = c * 256 + t;
                CT[(size_t)r * 1024 + o] = dotg256(wp.cw4 + (size_t)o * 256, xb_) + wp.cb4[o];
            }
        } else {
            int r = bid - 32;                    // batch index
            xb_[t] = sB[r * 256 + t];
            __syncthreads();
            hb_[t] = lrelu(dotg256(wp.mw0 + (size_t)t * 256, xb_) + wp.mb0[t]);
            __syncthreads();
            xb_[t] = lrelu(dotg256(wp.mw1 + (size_t)t * 256, hb_) + wp.mb1[t]);
            __syncthreads();
            SMU[r * 256 + t] = dotg256(wp.mw2 + (size_t)t * 256, xb_) + wp.mb2[t];
        }
        return;
    }
    // -------- gram partials (unchanged inner loop) --------
    int gbid = bid - 36;
    int g = gbid >> 6, slice = gbid & 63;
    int w = tid >> 6, l = tid & 63;
    int col = l & 31, kq = l >> 5;
    int nbase = slice * 1024 + w * 256;     // stays inside one b
    int b = nbase >> 14, hw0 = nbase & 16383;
    const float* base = cA + (((size_t)(b * 256 + g * 32 + col)) << 14) + hw0 + kq * 8;
    f32x16 acc;
    #pragma unroll
    for (int r = 0; r < 16; r++) acc[r] = 0.f;
    float s0 = 0.f, s1 = 0.f;
    #pragma unroll 8
    for (int it = 0; it < 16; ++it) {
        float4 f0 = *(const float4*)(base + it * 16);
        float4 f1 = *(const float4*)(base + it * 16 + 4);
        s0 += (f0.x + f0.y) + (f0.z + f0.w);
        s1 += (f1.x + f1.y) + (f1.z + f1.w);
        bf16x8 v;
        v[0] = (__bf16)f0.x; v[1] = (__bf16)f0.y; v[2] = (__bf16)f0.z; v[3] = (__bf16)f0.w;
        v[4] = (__bf16)f1.x; v[5] = (__bf16)f1.y; v[6] = (__bf16)f1.z; v[7] = (__bf16)f1.w;
        acc = __builtin_amdgcn_mfma_f32_32x32x16_bf16(v, v, acc, 0, 0, 0);
    }
    __shared__ float red[4][1024];
    __shared__ float sxr[4][64];
    sxr[w][l] = s0 + s1;
    #pragma unroll
    for (int r = 0; r < 16; r++) {
        int i = (r & 3) + 8 * (r >> 2) + 4 * kq;   // 32x32 C/D layout
        red[w][i * 32 + col] = acc[r];
    }
    __syncthreads();
    for (int e = tid; e < 1024; e += 256)
        pSXY[(size_t)gbid * 1024 + e] = red[0][e] + red[1][e] + red[2][e] + red[3][e];
    if (tid < 32) {
        float v = 0.f;
        #pragma unroll
        for (int ww = 0; ww < 4; ww++) v += sxr[ww][tid] + sxr[ww][tid + 32];
        pSX[gbid * 32 + tid] = v;
    }
}

// ---------- K2: blocks 0..1023 color (+per-block M/T recompute, chunk0 writes eigen); 1024..1031 cov ----------
__global__ __launch_bounds__(256) void color_fused(const float* __restrict__ cA,
                                                   const float* __restrict__ CT,
                                                   const float* __restrict__ SMU,
                                                   const float* __restrict__ pSX,
                                                   const float* __restrict__ pSXY,
                                                   float* __restrict__ out) {
    __shared__ float sct[32 * 33];
    __shared__ float sctd[32 * 33];
    __shared__ float Ml[1024];
    __shared__ float tl[32];
    __shared__ float sxg[32];
    __shared__ float dinv[32];
    __shared__ float xs[2][2048];
    int bid = blockIdx.x;
    int tid = threadIdx.x;

    if (bid >= 1024) {
        // -------- cov output per group --------
        int g = bid - 1024;
        if (tid < 32) {
            float s = 0.f;
            #pragma unroll
            for (int sl = 0; sl < 64; sl++) s += pSX[(g * 64 + sl) * 32 + tid];
            sxg[tid] = s * (1.0f / NTOT);
        }
        __syncthreads();
        float* cov = out + OUT_COV + (size_t)g * 1024;
        for (int e = tid; e < 1024; e += 256) {
            float s = 0.f;
            #pragma unroll
            for (int sl = 0; sl < 64; sl++) s += pSXY[(size_t)(g * 64 + sl) * 1024 + e];
            int i = e >> 5, jj = e & 31;
            float vv = (s - NTOT * sxg[i] * sxg[jj]) * (1.0f / (NTOT - 1.0f));
            if (i == jj) vv += 1e-5f;
            cov[e] = vv;
        }
        return;
    }

    int bg = bid >> 5, chunk = bid & 31;
    int b = bg >> 3, g = bg & 7;

    // ---- prologue: recompute M (=alpha*UDU+0.6I) and T for this (b,g) ----
    for (int e = tid; e < 1024; e += 256) sct[(e >> 5) * 33 + (e & 31)] = CT[(size_t)bg * 1024 + e];
    if (tid < 32) {
        float s = 0.f;
        #pragma unroll
        for (int sl = 0; sl < 64; sl++) s += pSX[(g * 64 + sl) * 32 + tid];
        sxg[tid] = s * (1.0f / NTOT);
    }
    __syncthreads();
    if (tid < 32) {
        float s = 0.f;
        #pragma unroll
        for (int i = 0; i < 32; i++) { float v = sct[i * 33 + tid]; s = fmaf(v, v, s); }
        dinv[tid] = 1.0f / sqrtf(s);
    }
    __syncthreads();
    for (int e = tid; e < 1024; e += 256) {
        int i = e >> 5, j = e & 31;
        sctd[i * 33 + j] = sct[i * 33 + j] * dinv[j];   // = U[i][j]
    }
    __syncthreads();
    if (chunk == 0) {
        float* eig = out + OUT_EIG + (size_t)(g * 4 + b) * 1024;
        for (int e = tid; e < 1024; e += 256) eig[e] = sctd[(e >> 5) * 33 + (e & 31)];
    }
    for (int e = tid; e < 1024; e += 256) {
        int i = e >> 5, k = e & 31;
        float s = 0.f;
        #pragma unroll
        for (int j = 0; j < 32; j++) s = fmaf(sct[i * 33 + j], sctd[k * 33 + j], s);
        Ml[e] = ALPHA_W * s + (i == k ? (1.0f - ALPHA_W) : 0.0f);
    }
    __syncthreads();
    if (tid < 32) {
        float s = 0.f;
        #pragma unroll
        for (int k = 0; k < 32; k++) s = fmaf(Ml[tid * 32 + k], sxg[k], s);
        // T = alpha*SMU - alpha*sum(UDU*sxg); with Ml = alpha*UDU + 0.6I:
        // alpha*sum(UDU*sxg) = s - 0.6*sxg[t]
        tl[tid] = ALPHA_W * SMU[bg * 32 + tid] - s + (1.0f - ALPHA_W) * sxg[tid];
    }
    // (tile loop's first __syncthreads orders tl before use)

    // ---- main coloring loop (unchanged) ----
    int n = tid & 63, ih = tid >> 6;
    size_t cbase = (((size_t)(b * 256 + g * 32)) << 14) + chunk * 512;
    int srow = tid >> 3, scol = (tid & 7) * 8;
    size_t obase = (((size_t)(b * 256 + g * 32 + ih * 8)) << 14) + chunk * 512 + n;
    for (int tile = 0; tile < 8; ++tile) {
        const float* src = cA + cbase + (size_t)srow * 16384 + tile * 64 + scol;
        float4 u0 = *(const float4*)src;
        float4 u1 = *(const float4*)(src + 4);
        float* xd = &xs[tile & 1][srow * 64 + scol];
        *(float4*)xd = u0;
        *(float4*)(xd + 4) = u1;
        __syncthreads();
        const float* xb = xs[tile & 1];
        float acc[8];
        #pragma unroll
        for (int i = 0; i < 8; i++) acc[i] = tl[ih * 8 + i];
        #pragma unroll
        for (int k = 0; k < 32; k++) {
            float xv = xb[k * 64 + n];
            #pragma unroll
            for (int i = 0; i < 8; i++) acc[i] = fmaf(Ml[(ih * 8 + i) * 32 + k], xv, acc[i]);
        }
        float* dst = out + obase + tile * 64;
        #pragma unroll
        for (int i = 0; i < 8; i++) dst[(size_t)i << 14] = acc[i];
    }
}

extern "C" void kernel_launch(void* const* d_in, const int* in_sizes, int n_in,
                              void* d_out, int out_size, void* d_ws, size_t ws_size,
                              hipStream_t stream) {
    (void)in_sizes; (void)n_in; (void)out_size; (void)ws_size;
    const float* cA = (const float*)d_in[0];
    const float* sB = (const float*)d_in[1];
    WP wp;
    wp.cw0 = (const float*)d_in[3];  wp.cb0 = (const float*)d_in[4];
    wp.cw1 = (const float*)d_in[5];  wp.cb1 = (const float*)d_in[6];
    wp.cw2 = (const float*)d_in[7];  wp.cb2 = (const float*)d_in[8];
    wp.cw3 = (const float*)d_in[9];  wp.cb3 = (const float*)d_in[10];
    wp.cw4 = (const float*)d_in[11]; wp.cb4 = (const float*)d_in[12];
    wp.mw0 = (const float*)d_in[13]; wp.mb0 = (const float*)d_in[14];
    wp.mw1 = (const float*)d_in[15]; wp.mb1 = (const float*)d_in[16];
    wp.mw2 = (const float*)d_in[17]; wp.mb2 = (const float*)d_in[18];
    float* W = (float*)d_ws;
    float* out = (float*)d_out;

    fused_front<<<548, 256, 0, stream>>>(cA, sB, wp, W + WS_PSXY, W + WS_PSX,
                                         W + WS_CT, W + WS_SMU);
    color_fused<<<1032, 256, 0, stream>>>(cA, W + WS_CT, W + WS_SMU,
                                          W + WS_PSX, W + WS_PSXY, out);
}

// Round 2
// 234.686 us; speedup vs baseline: 1.0082x; 1.0082x over previous
//
#include <hip/hip_runtime.h>
#include <hip/hip_bf16.h>

typedef __bf16 bf16x8 __attribute__((ext_vector_type(8)));
typedef float  f32x16 __attribute__((ext_vector_type(16)));

#define ALPHA_W 0.4f
#define NTOT 65536.0f

// output layout (float elements): [out 4*256*128*128][cov 8*32*32][eigen 32*32*32]
#define OUT_MAIN 16777216
#define OUT_COV  (OUT_MAIN)
#define OUT_EIG  (OUT_MAIN + 8192)

// ws float offsets
#define WS_PSXY  0        // 512*1024 gram partials
#define WS_PSX   524288   // 512*32 channel-sum partials
#define WS_SMU   559104   // 4*256
#define WS_CT    560128   // 32*1024 s_CT

struct WP {
    const float* cw0; const float* cb0;
    const float* cw1; const float* cb1;
    const float* cw2; const float* cb2;
    const float* cw3; const float* cb3;
    const float* cw4; const float* cb4;
    const float* mw0; const float* mb0;
    const float* mw1; const float* mb1;
    const float* mw2; const float* mb2;
};

__device__ __forceinline__ float lrelu(float x) { return x >= 0.f ? x : 0.01f * x; }

// 64-MAC partial dot: w from global (16 float4 loads, all independent -> one latency round),
// x from LDS (broadcast across lanes sharing l).
__device__ __forceinline__ float dot64(const float* __restrict__ w, const float* __restrict__ x) {
    float a0 = 0.f, a1 = 0.f, a2 = 0.f, a3 = 0.f;
    #pragma unroll
    for (int i = 0; i < 64; i += 16) {
        float4 w0 = *(const float4*)(w + i);
        float4 w1 = *(const float4*)(w + i + 4);
        float4 w2 = *(const float4*)(w + i + 8);
        float4 w3 = *(const float4*)(w + i + 12);
        float4 x0 = *(const float4*)(x + i);
        float4 x1 = *(const float4*)(x + i + 4);
        float4 x2 = *(const float4*)(x + i + 8);
        float4 x3 = *(const float4*)(x + i + 12);
        a0 = fmaf(w0.x, x0.x, a0); a0 = fmaf(w0.y, x0.y, a0);
        a0 = fmaf(w0.z, x0.z, a0); a0 = fmaf(w0.w, x0.w, a0);
        a1 = fmaf(w1.x, x1.x, a1); a1 = fmaf(w1.y, x1.y, a1);
        a1 = fmaf(w1.z, x1.z, a1); a1 = fmaf(w1.w, x1.w, a1);
        a2 = fmaf(w2.x, x2.x, a2); a2 = fmaf(w2.y, x2.y, a2);
        a2 = fmaf(w2.z, x2.z, a2); a2 = fmaf(w2.w, x2.w, a2);
        a3 = fmaf(w3.x, x3.x, a3); a3 = fmaf(w3.y, x3.y, a3);
        a3 = fmaf(w3.z, x3.z, a3); a3 = fmaf(w3.w, x3.w, a3);
    }
    return (a0 + a1) + (a2 + a3);
}

// one 256-in x 256-out layer via 4-lane-split dots: 4 passes, each ~1 memory round trip.
// y may be LDS or global.
__device__ __forceinline__ void layer256(const float* __restrict__ w, const float* __restrict__ bias,
                                         const float* __restrict__ x, float* __restrict__ y,
                                         int tid, int act) {
    int l = tid & 3, oq = tid >> 2;
    const float* xr = x + l * 64;
    #pragma unroll 2
    for (int p = 0; p < 4; ++p) {
        int o = p * 64 + oq;
        float s = dot64(w + (size_t)o * 256 + l * 64, xr);
        s += __shfl_xor(s, 1, 64);
        s += __shfl_xor(s, 2, 64);
        if (l == 0) {
            float v = s + bias[o];
            y[o] = act ? lrelu(v) : v;
        }
    }
}

// ---------- K1: blocks 0..31 ct-MLP rows, 32..35 mu-MLP rows, 36..547 gram ----------
__global__ __launch_bounds__(256, 2) void gram_mlp(const float* __restrict__ cA,
                                                   const float* __restrict__ sB,
                                                   WP wp,
                                                   float* __restrict__ pSXY,
                                                   float* __restrict__ pSX,
                                                   float* __restrict__ CT,
                                                   float* __restrict__ SMU) {
    int bid = blockIdx.x;
    int tid = threadIdx.x;
    if (bid < 36) {
        __shared__ float xA[256], xB[256];
        int t = tid;
        if (bid < 32) {
            int r = bid;                         // r = b*8+g
            if (t < 32) xA[t] = sB[r * 32 + t];
            __syncthreads();
            // L0: 256 x 32 (8 loads in flight -> one round)
            {
                const float* wr = wp.cw0 + t * 32;
                float a0 = 0.f, a1 = 0.f;
                #pragma unroll
                for (int i = 0; i < 32; i += 8) {
                    float4 u0 = *(const float4*)(wr + i);
                    float4 u1 = *(const float4*)(wr + i + 4);
                    float4 x0 = *(const float4*)(xA + i);
                    float4 x1 = *(const float4*)(xA + i + 4);
                    a0 = fmaf(u0.x, x0.x, a0); a0 = fmaf(u0.y, x0.y, a0);
                    a0 = fmaf(u0.z, x0.z, a0); a0 = fmaf(u0.w, x0.w, a0);
                    a1 = fmaf(u1.x, x1.x, a1); a1 = fmaf(u1.y, x1.y, a1);
                    a1 = fmaf(u1.z, x1.z, a1); a1 = fmaf(u1.w, x1.w, a1);
                }
                xB[t] = lrelu(a0 + a1 + wp.cb0[t]);
            }
            __syncthreads();
            layer256(wp.cw1, wp.cb1, xB, xA, t, 1);
            __syncthreads();
            layer256(wp.cw2, wp.cb2, xA, xB, t, 1);
            __syncthreads();
            layer256(wp.cw3, wp.cb3, xB, xA, t, 1);
            __syncthreads();
            // L4: 1024 x 256, no act, straight to global
            int l = t & 3, oq = t >> 2;
            const float* xr = xA + l * 64;
            #pragma unroll 2
            for (int p = 0; p < 16; ++p) {
                int o = p * 64 + oq;
                float s = dot64(wp.cw4 + (size_t)o * 256 + l * 64, xr);
                s += __shfl_xor(s, 1, 64);
                s += __shfl_xor(s, 2, 64);
                if (l == 0) CT[(size_t)r * 1024 + o] = s + wp.cb4[o];
            }
        } else {
            int r = bid - 32;                    // batch index
            xA[t] = sB[r * 256 + t];
            __syncthreads();
            layer256(wp.mw0, wp.mb0, xA, xB, t, 1);
            __syncthreads();
            layer256(wp.mw1, wp.mb1, xB, xA, t, 1);
            __syncthreads();
            layer256(wp.mw2, wp.mb2, xA, SMU + r * 256, t, 0);
        }
        return;
    }
    // -------- gram partials (unchanged inner loop) --------
    int gbid = bid - 36;
    int g = gbid >> 6, slice = gbid & 63;
    int w = tid >> 6, l = tid & 63;
    int col = l & 31, kq = l >> 5;
    int nbase = slice * 1024 + w * 256;     // stays inside one b
    int b = nbase >> 14, hw0 = nbase & 16383;
    const float* base = cA + (((size_t)(b * 256 + g * 32 + col)) << 14) + hw0 + kq * 8;
    f32x16 acc;
    #pragma unroll
    for (int r = 0; r < 16; r++) acc[r] = 0.f;
    float s0 = 0.f, s1 = 0.f;
    #pragma unroll 8
    for (int it = 0; it < 16; ++it) {
        float4 f0 = *(const float4*)(base + it * 16);
        float4 f1 = *(const float4*)(base + it * 16 + 4);
        s0 += (f0.x + f0.y) + (f0.z + f0.w);
        s1 += (f1.x + f1.y) + (f1.z + f1.w);
        bf16x8 v;
        v[0] = (__bf16)f0.x; v[1] = (__bf16)f0.y; v[2] = (__bf16)f0.z; v[3] = (__bf16)f0.w;
        v[4] = (__bf16)f1.x; v[5] = (__bf16)f1.y; v[6] = (__bf16)f1.z; v[7] = (__bf16)f1.w;
        acc = __builtin_amdgcn_mfma_f32_32x32x16_bf16(v, v, acc, 0, 0, 0);
    }
    __shared__ float red[4][1024];
    __shared__ float sxr[4][64];
    sxr[w][l] = s0 + s1;
    #pragma unroll
    for (int r = 0; r < 16; r++) {
        int i = (r & 3) + 8 * (r >> 2) + 4 * kq;   // 32x32 C/D layout
        red[w][i * 32 + col] = acc[r];
    }
    __syncthreads();
    for (int e = tid; e < 1024; e += 256)
        pSXY[(size_t)gbid * 1024 + e] = red[0][e] + red[1][e] + red[2][e] + red[3][e];
    if (tid < 32) {
        float v = 0.f;
        #pragma unroll
        for (int ww = 0; ww < 4; ww++) v += sxr[ww][tid] + sxr[ww][tid + 32];
        pSX[gbid * 32 + tid] = v;
    }
}

// ---------- K2: blocks 0..1023 color (+per-block M/T recompute, chunk0 writes eigen); 1024..1031 cov ----------
__global__ __launch_bounds__(256) void color_fused(const float* __restrict__ cA,
                                                   const float* __restrict__ CT,
                                                   const float* __restrict__ SMU,
                                                   const float* __restrict__ pSX,
                                                   const float* __restrict__ pSXY,
                                                   float* __restrict__ out) {
    __shared__ float sct[32 * 33];
    __shared__ float sctd[32 * 33];
    __shared__ float Ml[1024];
    __shared__ float tl[32];
    __shared__ float sxg[32];
    __shared__ float dinv[32];
    __shared__ float xs[2][2048];
    int bid = blockIdx.x;
    int tid = threadIdx.x;

    if (bid >= 1024) {
        // -------- cov output per group --------
        int g = bid - 1024;
        if (tid < 32) {
            float s = 0.f;
            #pragma unroll
            for (int sl = 0; sl < 64; sl++) s += pSX[(g * 64 + sl) * 32 + tid];
            sxg[tid] = s * (1.0f / NTOT);
        }
        __syncthreads();
        float* cov = out + OUT_COV + (size_t)g * 1024;
        for (int e = tid; e < 1024; e += 256) {
            float s = 0.f;
            #pragma unroll
            for (int sl = 0; sl < 64; sl++) s += pSXY[(size_t)(g * 64 + sl) * 1024 + e];
            int i = e >> 5, jj = e & 31;
            float vv = (s - NTOT * sxg[i] * sxg[jj]) * (1.0f / (NTOT - 1.0f));
            if (i == jj) vv += 1e-5f;
            cov[e] = vv;
        }
        return;
    }

    int bg = bid >> 5, chunk = bid & 31;
    int b = bg >> 3, g = bg & 7;

    // ---- prologue: recompute M (=alpha*UDU+0.6I) and T for this (b,g) ----
    for (int e = tid; e < 1024; e += 256) sct[(e >> 5) * 33 + (e & 31)] = CT[(size_t)bg * 1024 + e];
    if (tid < 32) {
        float s = 0.f;
        #pragma unroll
        for (int sl = 0; sl < 64; sl++) s += pSX[(g * 64 + sl) * 32 + tid];
        sxg[tid] = s * (1.0f / NTOT);
    }
    __syncthreads();
    if (tid < 32) {
        float s = 0.f;
        #pragma unroll
        for (int i = 0; i < 32; i++) { float v = sct[i * 33 + tid]; s = fmaf(v, v, s); }
        dinv[tid] = 1.0f / sqrtf(s);
    }
    __syncthreads();
    for (int e = tid; e < 1024; e += 256) {
        int i = e >> 5, j = e & 31;
        sctd[i * 33 + j] = sct[i * 33 + j] * dinv[j];   // = U[i][j]
    }
    __syncthreads();
    if (chunk == 0) {
        float* eig = out + OUT_EIG + (size_t)(g * 4 + b) * 1024;
        for (int e = tid; e < 1024; e += 256) eig[e] = sctd[(e >> 5) * 33 + (e & 31)];
    }
    for (int e = tid; e < 1024; e += 256) {
        int i = e >> 5, k = e & 31;
        float s = 0.f;
        #pragma unroll
        for (int j = 0; j < 32; j++) s = fmaf(sct[i * 33 + j], sctd[k * 33 + j], s);
        Ml[e] = ALPHA_W * s + (i == k ? (1.0f - ALPHA_W) : 0.0f);
    }
    __syncthreads();
    if (tid < 32) {
        float s = 0.f;
        #pragma unroll
        for (int k = 0; k < 32; k++) s = fmaf(Ml[tid * 32 + k], sxg[k], s);
        // alpha*sum(UDU*sxg) = s - 0.6*sxg[t]  (Ml = alpha*UDU + 0.6I)
        tl[tid] = ALPHA_W * SMU[bg * 32 + tid] - s + (1.0f - ALPHA_W) * sxg[tid];
    }
    // (tile loop's first __syncthreads orders tl before use)

    // ---- main coloring loop with explicit register prefetch ----
    int n = tid & 63, ih = tid >> 6;
    size_t cbase = (((size_t)(b * 256 + g * 32)) << 14) + chunk * 512;
    int srow = tid >> 3, scol = (tid & 7) * 8;
    size_t obase = (((size_t)(b * 256 + g * 32 + ih * 8)) << 14) + chunk * 512 + n;
    const float* src0 = cA + cbase + (size_t)srow * 16384 + scol;
    float4 u0 = *(const float4*)src0;
    float4 u1 = *(const float4*)(src0 + 4);
    for (int tile = 0; tile < 8; ++tile) {
        float* xd = &xs[tile & 1][srow * 64 + scol];
        *(float4*)xd = u0;
        *(float4*)(xd + 4) = u1;
        if (tile < 7) {
            const float* src = cA + cbase + (size_t)srow * 16384 + (tile + 1) * 64 + scol;
            u0 = *(const float4*)src;
            u1 = *(const float4*)(src + 4);
        }
        __syncthreads();
        const float* xb = xs[tile & 1];
        float acc[8];
        #pragma unroll
        for (int i = 0; i < 8; i++) acc[i] = tl[ih * 8 + i];
        #pragma unroll
        for (int k = 0; k < 32; k++) {
            float xv = xb[k * 64 + n];
            #pragma unroll
            for (int i = 0; i < 8; i++) acc[i] = fmaf(Ml[(ih * 8 + i) * 32 + k], xv, acc[i]);
        }
        float* dst = out + obase + tile * 64;
        #pragma unroll
        for (int i = 0; i < 8; i++) dst[(size_t)i << 14] = acc[i];
    }
}

extern "C" void kernel_launch(void* const* d_in, const int* in_sizes, int n_in,
                              void* d_out, int out_size, void* d_ws, size_t ws_size,
                              hipStream_t stream) {
    (void)in_sizes; (void)n_in; (void)out_size; (void)ws_size;
    const float* cA = (const float*)d_in[0];
    const float* sB = (const float*)d_in[1];
    WP wp;
    wp.cw0 = (const float*)d_in[3];  wp.cb0 = (const float*)d_in[4];
    wp.cw1 = (const float*)d_in[5];  wp.cb1 = (const float*)d_in[6];
    wp.cw2 = (const float*)d_in[7];  wp.cb2 = (const float*)d_in[8];
    wp.cw3 = (const float*)d_in[9];  wp.cb3 = (const float*)d_in[10];
    wp.cw4 = (const float*)d_in[11]; wp.cb4 = (const float*)d_in[12];
    wp.mw0 = (const float*)d_in[13]; wp.mb0 = (const float*)d_in[14];
    wp.mw1 = (const float*)d_in[15]; wp.mb1 = (const float*)d_in[16];
    wp.mw2 = (const float*)d_in[17]; wp.mb2 = (const float*)d_in[18];
    float* W = (float*)d_ws;
    float* out = (float*)d_out;

    gram_mlp<<<548, 256, 0, stream>>>(cA, sB, wp, W + WS_PSXY, W + WS_PSX,
                                      W + WS_CT, W + WS_SMU);
    color_fused<<<1032, 256, 0, stream>>>(cA, W + WS_CT, W + WS_SMU,
                                          W + WS_PSX, W + WS_PSXY, out);
}